// Round 1
// baseline (2184.749 us; speedup 1.0000x reference)
//
#include <hip/hip_runtime.h>
#include <math.h>

#define D 128
#define F_RELU 1
#define F_ACC 2

__global__ __launch_bounds__(256) void k_zero_i32(int* __restrict__ p, int n) {
  int i = blockIdx.x * 256 + threadIdx.x;
  if (i < n) p[i] = 0;
}

__global__ __launch_bounds__(256) void k_count_deg(const int* __restrict__ dst,
                                                   int* __restrict__ deg, int E_) {
  int e = blockIdx.x * 256 + threadIdx.x;
  if (e < E_) atomicAdd(&deg[dst[e]], 1);
}

// block-level exclusive scan: 1024 elems/block (256 thr x 4)
__global__ __launch_bounds__(256) void k_scan1(const int* __restrict__ deg,
                                               int* __restrict__ row_start,
                                               int* __restrict__ bsums, int n) {
  __shared__ int tsum[256];
  int t = threadIdx.x;
  int base = blockIdx.x * 1024 + t * 4;
  int v[4], ex[4];
  int s = 0;
#pragma unroll
  for (int i = 0; i < 4; i++) {
    int idx = base + i;
    v[i] = (idx < n) ? deg[idx] : 0;
    ex[i] = s;
    s += v[i];
  }
  tsum[t] = s;
  __syncthreads();
  for (int off = 1; off < 256; off <<= 1) {
    int x = (t >= off) ? tsum[t - off] : 0;
    __syncthreads();
    tsum[t] += x;
    __syncthreads();
  }
  int texcl = tsum[t] - s;
#pragma unroll
  for (int i = 0; i < 4; i++) {
    int idx = base + i;
    if (idx < n) row_start[idx] = texcl + ex[i];
  }
  if (t == 255) bsums[blockIdx.x] = tsum[255];
}

__global__ __launch_bounds__(128) void k_scan2(int* __restrict__ bsums, int nb) {
  __shared__ int bs[128];
  int t = threadIdx.x;
  int orig = (t < nb) ? bsums[t] : 0;
  bs[t] = orig;
  __syncthreads();
  for (int off = 1; off < 128; off <<= 1) {
    int x = (t >= off) ? bs[t - off] : 0;
    __syncthreads();
    bs[t] += x;
    __syncthreads();
  }
  if (t < nb) bsums[t] = bs[t] - orig;  // exclusive prefix of block sums
}

__global__ __launch_bounds__(256) void k_scan3(int* __restrict__ row_start,
                                               const int* __restrict__ bsums,
                                               const int* __restrict__ deg,
                                               int* __restrict__ fill_cnt,
                                               float* __restrict__ inv_deg, int n) {
  int i = blockIdx.x * 256 + threadIdx.x;
  if (i < n) {
    int rs = row_start[i] + bsums[i >> 10];
    row_start[i] = rs;
    fill_cnt[i] = rs;
    int d = deg[i];
    inv_deg[i] = 1.0f / (float)(d > 0 ? d : 1);
  }
}

__global__ __launch_bounds__(256) void k_fill_csr(const int* __restrict__ src,
                                                  const int* __restrict__ dst,
                                                  int* __restrict__ fill_cnt,
                                                  int* __restrict__ csr, int E_) {
  int e = blockIdx.x * 256 + threadIdx.x;
  if (e < E_) {
    int dnode = dst[e];
    int slot = atomicAdd(&fill_cnt[dnode], 1);
    csr[slot] = src[e];
  }
}

// one wave (64 lanes) per node; lane handles 2 columns (float2)
__global__ __launch_bounds__(256) void k_aggregate(const float* __restrict__ h,
                                                   float* __restrict__ agg,
                                                   const int* __restrict__ row_start,
                                                   const int* __restrict__ deg,
                                                   const float* __restrict__ inv_deg,
                                                   const int* __restrict__ csr, int n) {
  int w = (blockIdx.x * 256 + threadIdx.x) >> 6;
  int lane = threadIdx.x & 63;
  if (w >= n) return;
  int s0 = row_start[w];
  int dcount = deg[w];
  int col = lane * 2;
  float ax = 0.f, ay = 0.f;
  for (int e = 0; e < dcount; ++e) {
    int s = csr[s0 + e];
    float2 v = *(const float2*)(h + (size_t)s * D + col);
    ax += v.x;
    ay += v.y;
  }
  float iv = inv_deg[w];
  float2 o;
  o.x = ax * iv;
  o.y = ay * iv;
  *(float2*)(agg + (size_t)w * D + col) = o;
}

// out[r][j] = dot(A[r,:], W[j,:]) (+bias) (+=out) (relu); 64 rows x 128 cols per block
__global__ __launch_bounds__(256) void k_gemm(const float* __restrict__ A,
                                              const float* __restrict__ W,
                                              const float* __restrict__ bias,
                                              float* __restrict__ out, int n, int flags) {
  __shared__ float Ws[128][132];
  __shared__ float As[64][132];
  int t = threadIdx.x;
  int r0 = blockIdx.x * 64;
  for (int i = t; i < 128 * 128; i += 256) {
    Ws[i >> 7][i & 127] = W[i];
  }
  for (int i = t; i < 64 * 128; i += 256) {
    int r = i >> 7, k = i & 127;
    int gr = r0 + r;
    As[r][k] = (gr < n) ? A[(size_t)gr * D + k] : 0.f;
  }
  __syncthreads();

  float acc[8][4];
#pragma unroll
  for (int i = 0; i < 8; i++) {
#pragma unroll
    for (int j = 0; j < 4; j++) acc[i][j] = 0.f;
  }
  int cb = t & 31;          // cols cb + 32*j
  int rb = (t >> 5) * 8;    // rows rb + i

  for (int k = 0; k < 128; k += 4) {
    float4 w4[4];
#pragma unroll
    for (int j = 0; j < 4; j++) w4[j] = *(const float4*)&Ws[cb + 32 * j][k];
#pragma unroll
    for (int i = 0; i < 8; i++) {
      float4 a4 = *(const float4*)&As[rb + i][k];
#pragma unroll
      for (int j = 0; j < 4; j++) {
        acc[i][j] += a4.x * w4[j].x;
        acc[i][j] += a4.y * w4[j].y;
        acc[i][j] += a4.z * w4[j].z;
        acc[i][j] += a4.w * w4[j].w;
      }
    }
  }

#pragma unroll
  for (int i = 0; i < 8; i++) {
    int gr = r0 + rb + i;
    if (gr < n) {
#pragma unroll
      for (int j = 0; j < 4; j++) {
        int c = cb + 32 * j;
        float v = acc[i][j];
        if (bias) v += bias[c];
        if (flags & F_ACC) v += out[(size_t)gr * D + c];
        if (flags & F_RELU) v = fmaxf(v, 0.f);
        out[(size_t)gr * D + c] = v;
      }
    }
  }
}

// in-place row L2-normalize then relu; one wave per row
__global__ __launch_bounds__(256) void k_norm_relu(float* __restrict__ x, int n) {
  int w = (blockIdx.x * 256 + threadIdx.x) >> 6;
  int lane = threadIdx.x & 63;
  if (w >= n) return;
  float2 v = *(float2*)(x + (size_t)w * D + lane * 2);
  float ss = v.x * v.x + v.y * v.y;
#pragma unroll
  for (int off = 32; off > 0; off >>= 1) ss += __shfl_xor(ss, off);
  float scale = 1.0f / fmaxf(sqrtf(ss), 1e-12f);
  v.x = fmaxf(v.x * scale, 0.f);
  v.y = fmaxf(v.y * scale, 0.f);
  *(float2*)(x + (size_t)w * D + lane * 2) = v;
}

extern "C" void kernel_launch(void* const* d_in, const int* in_sizes, int n_in,
                              void* d_out, int out_size, void* d_ws, size_t ws_size,
                              hipStream_t stream) {
  const float* x   = (const float*)d_in[0];
  const int*   ei  = (const int*)d_in[1];
  const float* Wp  = (const float*)d_in[2];
  const float* bp  = (const float*)d_in[3];
  const float* Wl  = (const float*)d_in[4];
  const float* bl  = (const float*)d_in[5];
  const float* Wr  = (const float*)d_in[6];
  const float* Wlo = (const float*)d_in[7];
  const float* blo = (const float*)d_in[8];
  const float* Wro = (const float*)d_in[9];
  float* out = (float*)d_out;

  const int N = in_sizes[0] / D;  // 100000
  const int E = in_sizes[1] / 2;  // 1600000
  const int* srcIdx = ei;
  const int* dstIdx = ei + E;

  // workspace layout (~110 MB)
  float* h   = (float*)d_ws;                 // N*D f32
  float* agg = h + (size_t)N * D;            // N*D f32
  int* deg       = (int*)(agg + (size_t)N * D);  // N
  int* row_start = deg + N;                      // N
  int* fill_cnt  = row_start + N;                // N
  float* inv_deg = (float*)(fill_cnt + N);       // N
  int* bsums     = (int*)(inv_deg + N);          // 256
  int* csr       = bsums + 256;                  // E

  int gN  = (N + 255) / 256;
  int gE  = (E + 255) / 256;
  int NB  = (N + 1023) / 1024;
  int gG  = (N + 63) / 64;
  int gW  = (N + 3) / 4;

  // ---- CSR build ----
  k_zero_i32<<<gN, 256, 0, stream>>>(deg, N);
  k_count_deg<<<gE, 256, 0, stream>>>(dstIdx, deg, E);
  k_scan1<<<NB, 256, 0, stream>>>(deg, row_start, bsums, N);
  k_scan2<<<1, 128, 0, stream>>>(bsums, NB);
  k_scan3<<<gN, 256, 0, stream>>>(row_start, bsums, deg, fill_cnt, inv_deg, N);
  k_fill_csr<<<gE, 256, 0, stream>>>(srcIdx, dstIdx, fill_cnt, csr, E);

  // ---- layer 0 ----  x0 = x (input), x1 -> d_out
  k_gemm<<<gG, 256, 0, stream>>>(x, Wp, bp, h, N, F_RELU);             // h = relu(x@Wp0.T+bp0)
  k_aggregate<<<gW, 256, 0, stream>>>(h, agg, row_start, deg, inv_deg, csr, N);
  k_gemm<<<gG, 256, 0, stream>>>(agg, Wl, bl, out, N, 0);              // out = agg@Wl0.T+bl0
  k_gemm<<<gG, 256, 0, stream>>>(x, Wr, nullptr, out, N, F_ACC);       // out += x@Wr0.T
  k_norm_relu<<<gW, 256, 0, stream>>>(out, N);                         // x1 in d_out

  // ---- layer 1 ----  x1 = d_out, x2 -> h
  k_gemm<<<gG, 256, 0, stream>>>(out, Wp + D * D, bp + D, h, N, F_RELU);
  k_aggregate<<<gW, 256, 0, stream>>>(h, agg, row_start, deg, inv_deg, csr, N);
  k_gemm<<<gG, 256, 0, stream>>>(agg, Wl + D * D, bl + D, h, N, 0);    // h dead, reuse as x2
  k_gemm<<<gG, 256, 0, stream>>>(out, Wr + D * D, nullptr, h, N, F_ACC);
  k_norm_relu<<<gW, 256, 0, stream>>>(h, N);                           // x2 in h

  // ---- final layer ----  (no projection, no normalize)
  k_aggregate<<<gW, 256, 0, stream>>>(h, agg, row_start, deg, inv_deg, csr, N);
  k_gemm<<<gG, 256, 0, stream>>>(agg, Wlo, blo, out, N, 0);
  k_gemm<<<gG, 256, 0, stream>>>(h, Wro, nullptr, out, N, F_ACC);
}

// Round 2
// 760.356 us; speedup vs baseline: 2.8733x; 2.8733x over previous
//
#include <hip/hip_runtime.h>
#include <math.h>

#define D 128

typedef short s8v __attribute__((ext_vector_type(8)));
typedef float f32x4 __attribute__((ext_vector_type(4)));

__device__ __forceinline__ unsigned short f2bf(float f) {
  union { float f; unsigned u; } c; c.f = f;
  unsigned u = c.u;
  unsigned r = (u + 0x7fffu + ((u >> 16) & 1u)) >> 16;
  return (unsigned short)r;
}
__device__ __forceinline__ float bf2f(unsigned short b) {
  union { unsigned u; float f; } c; c.u = ((unsigned)b) << 16;
  return c.f;
}

// ---------------- CSR build ----------------
__global__ __launch_bounds__(256) void k_zero_i32(int* __restrict__ p, int n) {
  int i = blockIdx.x * 256 + threadIdx.x;
  if (i < n) p[i] = 0;
}

__global__ __launch_bounds__(256) void k_count_deg(const int* __restrict__ dst,
                                                   int* __restrict__ deg, int E_) {
  int e = blockIdx.x * 256 + threadIdx.x;
  if (e < E_) atomicAdd(&deg[dst[e]], 1);
}

__global__ __launch_bounds__(256) void k_scan1(const int* __restrict__ deg,
                                               int* __restrict__ row_start,
                                               int* __restrict__ bsums, int n) {
  __shared__ int tsum[256];
  int t = threadIdx.x;
  int base = blockIdx.x * 1024 + t * 4;
  int v[4], ex[4];
  int s = 0;
#pragma unroll
  for (int i = 0; i < 4; i++) {
    int idx = base + i;
    v[i] = (idx < n) ? deg[idx] : 0;
    ex[i] = s;
    s += v[i];
  }
  tsum[t] = s;
  __syncthreads();
  for (int off = 1; off < 256; off <<= 1) {
    int x = (t >= off) ? tsum[t - off] : 0;
    __syncthreads();
    tsum[t] += x;
    __syncthreads();
  }
  int texcl = tsum[t] - s;
#pragma unroll
  for (int i = 0; i < 4; i++) {
    int idx = base + i;
    if (idx < n) row_start[idx] = texcl + ex[i];
  }
  if (t == 255) bsums[blockIdx.x] = tsum[255];
}

__global__ __launch_bounds__(128) void k_scan2(int* __restrict__ bsums, int nb) {
  __shared__ int bs[128];
  int t = threadIdx.x;
  int orig = (t < nb) ? bsums[t] : 0;
  bs[t] = orig;
  __syncthreads();
  for (int off = 1; off < 128; off <<= 1) {
    int x = (t >= off) ? bs[t - off] : 0;
    __syncthreads();
    bs[t] += x;
    __syncthreads();
  }
  if (t < nb) bsums[t] = bs[t] - orig;
}

__global__ __launch_bounds__(256) void k_scan3(int* __restrict__ row_start,
                                               const int* __restrict__ bsums,
                                               const int* __restrict__ deg,
                                               int* __restrict__ fill_cnt,
                                               float* __restrict__ inv_deg, int n) {
  int i = blockIdx.x * 256 + threadIdx.x;
  if (i < n) {
    int rs = row_start[i] + bsums[i >> 10];
    row_start[i] = rs;
    fill_cnt[i] = rs;
    int d = deg[i];
    inv_deg[i] = 1.0f / (float)(d > 0 ? d : 1);
  }
}

__global__ __launch_bounds__(256) void k_fill_csr(const int* __restrict__ src,
                                                  const int* __restrict__ dst,
                                                  int* __restrict__ fill_cnt,
                                                  int* __restrict__ csr, int E_) {
  int e = blockIdx.x * 256 + threadIdx.x;
  if (e < E_) {
    int dnode = dst[e];
    int slot = atomicAdd(&fill_cnt[dnode], 1);
    csr[slot] = src[e];
  }
}

// ---------------- fp32 -> bf16 convert (4 elems/thread) ----------------
__global__ __launch_bounds__(256) void k_cvt(const float* __restrict__ in,
                                             unsigned short* __restrict__ out, int n4) {
  int i = blockIdx.x * 256 + threadIdx.x;
  if (i >= n4) return;
  float4 a = ((const float4*)in)[i];
  ushort4 o;
  o.x = f2bf(a.x); o.y = f2bf(a.y); o.z = f2bf(a.z); o.w = f2bf(a.w);
  ((ushort4*)out)[i] = o;
}

// ---------------- mean aggregation (bf16 in/out, fp32 acc) ----------------
__global__ __launch_bounds__(256) void k_aggregate(const unsigned short* __restrict__ h,
                                                   unsigned short* __restrict__ agg,
                                                   const int* __restrict__ row_start,
                                                   const int* __restrict__ deg,
                                                   const float* __restrict__ inv_deg,
                                                   const int* __restrict__ csr, int n) {
  int w = (blockIdx.x * 256 + threadIdx.x) >> 6;
  int lane = threadIdx.x & 63;
  if (w >= n) return;
  int s0 = row_start[w];
  int dc = deg[w];
  float ax = 0.f, ay = 0.f, bx = 0.f, by = 0.f;
  int e = 0;
  for (; e + 1 < dc; e += 2) {
    int sA = csr[s0 + e];
    int sB = csr[s0 + e + 1];
    unsigned vA = *(const unsigned*)(h + (size_t)sA * D + lane * 2);
    unsigned vB = *(const unsigned*)(h + (size_t)sB * D + lane * 2);
    ax += bf2f((unsigned short)(vA & 0xffff));
    ay += bf2f((unsigned short)(vA >> 16));
    bx += bf2f((unsigned short)(vB & 0xffff));
    by += bf2f((unsigned short)(vB >> 16));
  }
  if (e < dc) {
    int sA = csr[s0 + e];
    unsigned vA = *(const unsigned*)(h + (size_t)sA * D + lane * 2);
    ax += bf2f((unsigned short)(vA & 0xffff));
    ay += bf2f((unsigned short)(vA >> 16));
  }
  float iv = inv_deg[w];
  float ox = (ax + bx) * iv;
  float oy = (ay + by) * iv;
  unsigned o = ((unsigned)f2bf(oy) << 16) | (unsigned)f2bf(ox);
  *(unsigned*)(agg + (size_t)w * D + lane * 2) = o;
}

// ---------------- projection GEMM: out = relu(A @ W^T + b) -> bf16 ----------------
// block = 256 thr = 4 waves; wave = 16 rows x 128 cols; MFMA 16x16x32 bf16.
// Fragment k-map: lane l, elem j -> k = 8*(l>>4)+j (consistent for A and B => correct).
__global__ __launch_bounds__(256) void k_gemm_proj(const unsigned short* __restrict__ A,
                                                   const unsigned short* __restrict__ W,
                                                   const float* __restrict__ bias,
                                                   unsigned short* __restrict__ out, int n) {
  int t = threadIdx.x;
  int wv = t >> 6, l = t & 63, lg = l >> 4, ln = l & 15;
  int rb = blockIdx.x * 64 + wv * 16;
  int arow = rb + ln;
  if (arow >= n) arow = n - 1;
  const s8v* Ap = (const s8v*)(A + (size_t)arow * D + lg * 8);
  f32x4 acc[8];
#pragma unroll
  for (int f = 0; f < 8; ++f) acc[f] = (f32x4){0.f, 0.f, 0.f, 0.f};

#pragma unroll
  for (int ks = 0; ks < 4; ++ks) {
    s8v a = Ap[ks * 4];
#pragma unroll
    for (int f = 0; f < 8; ++f) {
      const s8v* Bp = (const s8v*)(W + (size_t)(f * 16 + ln) * D + lg * 8);
      s8v b = Bp[ks * 4];
      acc[f] = __builtin_amdgcn_mfma_f32_16x16x32_bf16(a, b, acc[f], 0, 0, 0);
    }
  }

#pragma unroll
  for (int r = 0; r < 4; ++r) {
    int gr = rb + 4 * lg + r;
    if (gr < n) {
#pragma unroll
      for (int f = 0; f < 8; ++f) {
        int c = f * 16 + ln;
        float v = acc[f][r] + bias[c];
        v = fmaxf(v, 0.f);
        out[(size_t)gr * D + c] = f2bf(v);
      }
    }
  }
}

// ---------------- dual GEMM: A1@W1^T + b + A2@W2^T, epilogue by MODE ----------------
// MODE 0: L2-normalize rows then relu, store bf16. MODE 1: store fp32.
template <int MODE>
__global__ __launch_bounds__(256) void k_gemm_dual(const unsigned short* __restrict__ A1,
                                                   const unsigned short* __restrict__ W1,
                                                   const float* __restrict__ bias,
                                                   const unsigned short* __restrict__ A2,
                                                   const unsigned short* __restrict__ W2,
                                                   void* __restrict__ outv, int n) {
  int t = threadIdx.x;
  int wv = t >> 6, l = t & 63, lg = l >> 4, ln = l & 15;
  int rb = blockIdx.x * 64 + wv * 16;
  int arow = rb + ln;
  if (arow >= n) arow = n - 1;
  const s8v* A1p = (const s8v*)(A1 + (size_t)arow * D + lg * 8);
  const s8v* A2p = (const s8v*)(A2 + (size_t)arow * D + lg * 8);
  f32x4 acc[8];
#pragma unroll
  for (int f = 0; f < 8; ++f) acc[f] = (f32x4){0.f, 0.f, 0.f, 0.f};

#pragma unroll
  for (int ks = 0; ks < 4; ++ks) {
    s8v a1 = A1p[ks * 4];
    s8v a2 = A2p[ks * 4];
#pragma unroll
    for (int f = 0; f < 8; ++f) {
      const s8v* B1p = (const s8v*)(W1 + (size_t)(f * 16 + ln) * D + lg * 8);
      s8v b1 = B1p[ks * 4];
      acc[f] = __builtin_amdgcn_mfma_f32_16x16x32_bf16(a1, b1, acc[f], 0, 0, 0);
    }
#pragma unroll
    for (int f = 0; f < 8; ++f) {
      const s8v* B2p = (const s8v*)(W2 + (size_t)(f * 16 + ln) * D + lg * 8);
      s8v b2 = B2p[ks * 4];
      acc[f] = __builtin_amdgcn_mfma_f32_16x16x32_bf16(a2, b2, acc[f], 0, 0, 0);
    }
  }

#pragma unroll
  for (int r = 0; r < 4; ++r) {
    int gr = rb + 4 * lg + r;
    float v[8];
#pragma unroll
    for (int f = 0; f < 8; ++f) v[f] = acc[f][r] + bias[f * 16 + ln];
    if (MODE == 0) {
      float ss = 0.f;
#pragma unroll
      for (int f = 0; f < 8; ++f) ss += v[f] * v[f];
      // reduce across the 16 lanes (ln) sharing this row
      ss += __shfl_xor(ss, 1);
      ss += __shfl_xor(ss, 2);
      ss += __shfl_xor(ss, 4);
      ss += __shfl_xor(ss, 8);
      float sc = 1.0f / fmaxf(sqrtf(ss), 1e-12f);
      if (gr < n) {
        unsigned short* out = (unsigned short*)outv;
#pragma unroll
        for (int f = 0; f < 8; ++f) {
          float o = fmaxf(v[f] * sc, 0.f);
          out[(size_t)gr * D + f * 16 + ln] = f2bf(o);
        }
      }
    } else {
      if (gr < n) {
        float* out = (float*)outv;
#pragma unroll
        for (int f = 0; f < 8; ++f) out[(size_t)gr * D + f * 16 + ln] = v[f];
      }
    }
  }
}

extern "C" void kernel_launch(void* const* d_in, const int* in_sizes, int n_in,
                              void* d_out, int out_size, void* d_ws, size_t ws_size,
                              hipStream_t stream) {
  const float* x   = (const float*)d_in[0];
  const int*   ei  = (const int*)d_in[1];
  const float* Wp  = (const float*)d_in[2];
  const float* bp  = (const float*)d_in[3];
  const float* Wl  = (const float*)d_in[4];
  const float* bl  = (const float*)d_in[5];
  const float* Wr  = (const float*)d_in[6];
  const float* Wlo = (const float*)d_in[7];
  const float* blo = (const float*)d_in[8];
  const float* Wro = (const float*)d_in[9];

  const int N = in_sizes[0] / D;  // 100000
  const int E = in_sizes[1] / 2;  // 1600000
  const int* srcIdx = ei;
  const int* dstIdx = ei + E;

  const size_t ND = (size_t)N * D;

  // workspace layout (bf16 buffers as ushort)
  unsigned short* xb   = (unsigned short*)d_ws;   // N*D
  unsigned short* h    = xb + ND;                 // N*D
  unsigned short* aggB = h + ND;                  // N*D
  unsigned short* x2   = aggB + ND;               // N*D
  unsigned short* Wb   = x2 + ND;                 // 8 * 16384
  int* deg       = (int*)(Wb + 8 * 16384);
  int* row_start = deg + N;
  int* fill_cnt  = row_start + N;
  float* inv_deg = (float*)(fill_cnt + N);
  int* bsums     = (int*)(inv_deg + N);           // 256
  int* csr       = bsums + 256;                   // E

  // bf16 weight slots
  unsigned short* Wpb0 = Wb;                   // 16384 each
  unsigned short* Wpb1 = Wb + 16384;
  unsigned short* Wlb0 = Wb + 2 * 16384;
  unsigned short* Wlb1 = Wb + 3 * 16384;
  unsigned short* Wrb0 = Wb + 4 * 16384;
  unsigned short* Wrb1 = Wb + 5 * 16384;
  unsigned short* Wlob = Wb + 6 * 16384;
  unsigned short* Wrob = Wb + 7 * 16384;

  // x1 (layer-1 output, bf16) lives in d_out scratch space (overwritten at the end)
  unsigned short* x1 = (unsigned short*)d_out;

  int gN = (N + 255) / 256;
  int gE = (E + 255) / 256;
  int NB = (N + 1023) / 1024;
  int gG = (N + 63) / 64;     // GEMM blocks (64 rows each)
  int gW = (N + 3) / 4;       // wave-per-node kernels

  // ---- conversions ----
  k_cvt<<<(int)((ND / 4 + 255) / 256), 256, 0, stream>>>(x, xb, (int)(ND / 4));
  k_cvt<<<32, 256, 0, stream>>>(Wp, Wpb0, 8192);   // covers both layers (2*16384)
  k_cvt<<<32, 256, 0, stream>>>(Wl, Wlb0, 8192);
  k_cvt<<<32, 256, 0, stream>>>(Wr, Wrb0, 8192);
  k_cvt<<<16, 256, 0, stream>>>(Wlo, Wlob, 4096);
  k_cvt<<<16, 256, 0, stream>>>(Wro, Wrob, 4096);

  // ---- CSR build ----
  k_zero_i32<<<gN, 256, 0, stream>>>(deg, N);
  k_count_deg<<<gE, 256, 0, stream>>>(dstIdx, deg, E);
  k_scan1<<<NB, 256, 0, stream>>>(deg, row_start, bsums, N);
  k_scan2<<<1, 128, 0, stream>>>(bsums, NB);
  k_scan3<<<gN, 256, 0, stream>>>(row_start, bsums, deg, fill_cnt, inv_deg, N);
  k_fill_csr<<<gE, 256, 0, stream>>>(srcIdx, dstIdx, fill_cnt, csr, E);

  // ---- layer 0 ----
  k_gemm_proj<<<gG, 256, 0, stream>>>(xb, Wpb0, bp, h, N);
  k_aggregate<<<gW, 256, 0, stream>>>(h, aggB, row_start, deg, inv_deg, csr, N);
  k_gemm_dual<0><<<gG, 256, 0, stream>>>(aggB, Wlb0, bl, xb, Wrb0, (void*)x1, N);

  // ---- layer 1 ----
  k_gemm_proj<<<gG, 256, 0, stream>>>(x1, Wpb1, bp + D, h, N);
  k_aggregate<<<gW, 256, 0, stream>>>(h, aggB, row_start, deg, inv_deg, csr, N);
  k_gemm_dual<0><<<gG, 256, 0, stream>>>(aggB, Wlb1, bl + D, x1, Wrb1, (void*)x2, N);

  // ---- final layer ----
  k_aggregate<<<gW, 256, 0, stream>>>(x2, aggB, row_start, deg, inv_deg, csr, N);
  k_gemm_dual<1><<<gG, 256, 0, stream>>>(aggB, Wlob, blo, x2, Wrob, d_out, N);
}

// Round 3
// 603.292 us; speedup vs baseline: 3.6214x; 1.2603x over previous
//
#include <hip/hip_runtime.h>
#include <math.h>

#define D 128

typedef short s8v __attribute__((ext_vector_type(8)));
typedef float f32x4 __attribute__((ext_vector_type(4)));

__device__ __forceinline__ unsigned short f2bf(float f) {
  union { float f; unsigned u; } c; c.f = f;
  unsigned u = c.u;
  unsigned r = (u + 0x7fffu + ((u >> 16) & 1u)) >> 16;
  return (unsigned short)r;
}
__device__ __forceinline__ float bf2f(unsigned short b) {
  union { unsigned u; float f; } c; c.u = ((unsigned)b) << 16;
  return c.f;
}

// ---------------- merged weight cvt + deg zero ----------------
// 8*16384 bf16 elems = 32768 float4 chunks; grid 128 x 256.
__global__ __launch_bounds__(256) void k_cvt_w(const float* __restrict__ Wp,
                                               const float* __restrict__ Wl,
                                               const float* __restrict__ Wr,
                                               const float* __restrict__ Wlo,
                                               const float* __restrict__ Wro,
                                               unsigned short* __restrict__ Wb,
                                               int* __restrict__ deg, int n) {
  int i = blockIdx.x * 256 + threadIdx.x;  // float4 units, 0..32767
  const float* s;
  int off;
  if (i < 8192)       { s = Wp;  off = 0; }
  else if (i < 16384) { s = Wl;  off = 8192; }
  else if (i < 24576) { s = Wr;  off = 16384; }
  else if (i < 28672) { s = Wlo; off = 24576; }
  else                { s = Wro; off = 28672; }
  float4 a = ((const float4*)s)[i - off];
  ushort4 o;
  o.x = f2bf(a.x); o.y = f2bf(a.y); o.z = f2bf(a.z); o.w = f2bf(a.w);
  ((ushort4*)Wb)[i] = o;
  for (int j = i; j < n; j += 32768) deg[j] = 0;
}

__global__ __launch_bounds__(256) void k_count_deg(const int* __restrict__ dst,
                                                   int* __restrict__ deg, int E_) {
  int e = blockIdx.x * 256 + threadIdx.x;
  if (e < E_) atomicAdd(&deg[dst[e]], 1);
}

__global__ __launch_bounds__(256) void k_scan1(const int* __restrict__ deg,
                                               int* __restrict__ row_start,
                                               int* __restrict__ bsums, int n) {
  __shared__ int tsum[256];
  int t = threadIdx.x;
  int base = blockIdx.x * 1024 + t * 4;
  int v[4], ex[4];
  int s = 0;
#pragma unroll
  for (int i = 0; i < 4; i++) {
    int idx = base + i;
    v[i] = (idx < n) ? deg[idx] : 0;
    ex[i] = s;
    s += v[i];
  }
  tsum[t] = s;
  __syncthreads();
  for (int off = 1; off < 256; off <<= 1) {
    int x = (t >= off) ? tsum[t - off] : 0;
    __syncthreads();
    tsum[t] += x;
    __syncthreads();
  }
  int texcl = tsum[t] - s;
#pragma unroll
  for (int i = 0; i < 4; i++) {
    int idx = base + i;
    if (idx < n) row_start[idx] = texcl + ex[i];
  }
  if (t == 255) bsums[blockIdx.x] = tsum[255];
}

__global__ __launch_bounds__(128) void k_scan2(int* __restrict__ bsums, int nb) {
  __shared__ int bs[128];
  int t = threadIdx.x;
  int orig = (t < nb) ? bsums[t] : 0;
  bs[t] = orig;
  __syncthreads();
  for (int off = 1; off < 128; off <<= 1) {
    int x = (t >= off) ? bs[t - off] : 0;
    __syncthreads();
    bs[t] += x;
    __syncthreads();
  }
  if (t < nb) bsums[t] = bs[t] - orig;
}

__global__ __launch_bounds__(256) void k_scan3(int* __restrict__ row_start,
                                               const int* __restrict__ bsums,
                                               const int* __restrict__ deg,
                                               float* __restrict__ inv_deg, int n) {
  int i = blockIdx.x * 256 + threadIdx.x;
  if (i < n) {
    row_start[i] += bsums[i >> 10];
    int d = deg[i];
    inv_deg[i] = 1.0f / (float)(d > 0 ? d : 1);
  }
}

// cursor[k] = pair-unit base of bucket k (bucket = 256 dst nodes)
__global__ __launch_bounds__(256) void k_cursor(const int* __restrict__ row_start,
                                                int* __restrict__ cursor, int n, int E_) {
  int k = blockIdx.x * 256 + threadIdx.x;
  if (k < 512) {
    int node = k << 8;
    cursor[k] = (node < n) ? row_start[node] : E_;
  }
}

// Pass A: bin (src,dst) pairs into bucket regions with LDS hist+rank.
// 4096 edges per block; grid = ceil(E/4096).
__global__ __launch_bounds__(256) void k_partA(const int* __restrict__ src,
                                               const int* __restrict__ dst,
                                               int* __restrict__ cursor,
                                               int2* __restrict__ pairs, int E_) {
  __shared__ int hist[512];
  __shared__ int gbase[512];
  int t = threadIdx.x;
  int base = blockIdx.x * 4096;
  hist[t] = 0;
  hist[t + 256] = 0;
  __syncthreads();
  int s_[16], d_[16];
#pragma unroll
  for (int i = 0; i < 16; i++) {
    int e = base + i * 256 + t;
    if (e < E_) {
      s_[i] = src[e];
      d_[i] = dst[e];
      atomicAdd(&hist[d_[i] >> 8], 1);
    } else {
      d_[i] = -1;
    }
  }
  __syncthreads();
#pragma unroll
  for (int kk = 0; kk < 2; kk++) {
    int k = t + kk * 256;
    int c = hist[k];
    if (c) gbase[k] = atomicAdd(&cursor[k], c);
    hist[k] = 0;
  }
  __syncthreads();
#pragma unroll
  for (int i = 0; i < 16; i++) {
    if (d_[i] >= 0) {
      int k = d_[i] >> 8;
      int r = atomicAdd(&hist[k], 1);
      pairs[gbase[k] + r] = make_int2(s_[i], d_[i]);
    }
  }
}

// Pass B: one block per bucket; LDS slot counters; csr region single-writer.
__global__ __launch_bounds__(256) void k_partB(const int2* __restrict__ pairs,
                                               const int* __restrict__ row_start,
                                               int* __restrict__ csr, int n, int E_) {
  __shared__ int cnt[256];
  int k = blockIdx.x;
  int t = threadIdx.x;
  int node0 = k << 8;
  int node = node0 + t;
  cnt[t] = (node < n) ? row_start[node] : 0;
  int pbeg = row_start[node0];
  int nodeEnd = node0 + 256;
  int pend = (nodeEnd < n) ? row_start[nodeEnd] : E_;
  __syncthreads();
  for (int p = pbeg + t; p < pend; p += 256) {
    int2 pr = pairs[p];
    int slot = atomicAdd(&cnt[pr.y & 255], 1);
    csr[slot] = pr.x;
  }
}

// ---------------- mean aggregation: wave/node, shfl-broadcast indices ----------------
__global__ __launch_bounds__(256) void k_aggregate(const unsigned short* __restrict__ h,
                                                   unsigned short* __restrict__ agg,
                                                   const int* __restrict__ row_start,
                                                   const int* __restrict__ deg,
                                                   const float* __restrict__ inv_deg,
                                                   const int* __restrict__ csr, int n) {
  int w = (blockIdx.x * 256 + threadIdx.x) >> 6;
  int lane = threadIdx.x & 63;
  if (w >= n) return;
  int s0 = row_start[w];
  int dc = deg[w];
  int half = lane >> 5, li = lane & 31;
  float a0 = 0.f, a1 = 0.f, a2 = 0.f, a3 = 0.f;
  for (int base = 0; base < dc; base += 64) {
    int m = min(64, dc - base);
    int idx = 0;
    if (lane < m) idx = csr[s0 + base + lane];
    int npairs = m >> 1;
    for (int j = 0; j < npairs; ++j) {
      int s = __shfl(idx, 2 * j + half);
      ushort4 v = *(const ushort4*)(h + (size_t)s * D + li * 4);
      a0 += bf2f(v.x); a1 += bf2f(v.y); a2 += bf2f(v.z); a3 += bf2f(v.w);
    }
    if (m & 1) {
      int s = __shfl(idx, m - 1);
      if (half == 0) {
        ushort4 v = *(const ushort4*)(h + (size_t)s * D + li * 4);
        a0 += bf2f(v.x); a1 += bf2f(v.y); a2 += bf2f(v.z); a3 += bf2f(v.w);
      }
    }
  }
  a0 += __shfl_xor(a0, 32);
  a1 += __shfl_xor(a1, 32);
  a2 += __shfl_xor(a2, 32);
  a3 += __shfl_xor(a3, 32);
  if (half == 0) {
    float iv = inv_deg[w];
    ushort4 o;
    o.x = f2bf(a0 * iv); o.y = f2bf(a1 * iv);
    o.z = f2bf(a2 * iv); o.w = f2bf(a3 * iv);
    *(ushort4*)(agg + (size_t)w * D + li * 4) = o;
  }
}

// ---------------- projection GEMM: out = relu(A @ W^T + b) -> bf16 ----------------
// CVT=1: A is fp32; also writes bf16 copy of A to xb_out (if non-null).
template <int CVT>
__global__ __launch_bounds__(256) void k_gemm_proj(const void* __restrict__ Av,
                                                   const unsigned short* __restrict__ W,
                                                   const float* __restrict__ bias,
                                                   unsigned short* __restrict__ out,
                                                   unsigned short* __restrict__ xb_out,
                                                   int n) {
  int t = threadIdx.x;
  int wv = t >> 6, l = t & 63, lg = l >> 4, ln = l & 15;
  int rb = blockIdx.x * 64 + wv * 16;
  int arow = rb + ln;
  if (arow >= n) arow = n - 1;

  s8v a[4];
  if (CVT) {
    const float* Af = (const float*)Av + (size_t)arow * D + lg * 8;
#pragma unroll
    for (int ks = 0; ks < 4; ++ks) {
      float4 f0 = *(const float4*)(Af + ks * 32);
      float4 f1 = *(const float4*)(Af + ks * 32 + 4);
      s8v av;
      av[0] = (short)f2bf(f0.x); av[1] = (short)f2bf(f0.y);
      av[2] = (short)f2bf(f0.z); av[3] = (short)f2bf(f0.w);
      av[4] = (short)f2bf(f1.x); av[5] = (short)f2bf(f1.y);
      av[6] = (short)f2bf(f1.z); av[7] = (short)f2bf(f1.w);
      a[ks] = av;
      if (xb_out) *(s8v*)(xb_out + (size_t)arow * D + lg * 8 + ks * 32) = av;
    }
  } else {
    const s8v* Ap = (const s8v*)((const unsigned short*)Av + (size_t)arow * D + lg * 8);
#pragma unroll
    for (int ks = 0; ks < 4; ++ks) a[ks] = Ap[ks * 4];
  }

  f32x4 acc[8];
#pragma unroll
  for (int f = 0; f < 8; ++f) acc[f] = (f32x4){0.f, 0.f, 0.f, 0.f};
#pragma unroll
  for (int ks = 0; ks < 4; ++ks) {
#pragma unroll
    for (int f = 0; f < 8; ++f) {
      const s8v* Bp = (const s8v*)(W + (size_t)(f * 16 + ln) * D + lg * 8);
      s8v b = Bp[ks * 4];
      acc[f] = __builtin_amdgcn_mfma_f32_16x16x32_bf16(a[ks], b, acc[f], 0, 0, 0);
    }
  }

#pragma unroll
  for (int r = 0; r < 4; ++r) {
    int gr = rb + 4 * lg + r;
    if (gr < n) {
#pragma unroll
      for (int f = 0; f < 8; ++f) {
        int c = f * 16 + ln;
        float v = acc[f][r] + bias[c];
        v = fmaxf(v, 0.f);
        out[(size_t)gr * D + c] = f2bf(v);
      }
    }
  }
}

// ---------------- dual GEMM: A1@W1^T + b + A2@W2^T ----------------
// MODE 0: L2-normalize rows then relu, store bf16. MODE 1: store fp32.
template <int MODE>
__global__ __launch_bounds__(256) void k_gemm_dual(const unsigned short* __restrict__ A1,
                                                   const unsigned short* __restrict__ W1,
                                                   const float* __restrict__ bias,
                                                   const unsigned short* __restrict__ A2,
                                                   const unsigned short* __restrict__ W2,
                                                   void* __restrict__ outv, int n) {
  int t = threadIdx.x;
  int wv = t >> 6, l = t & 63, lg = l >> 4, ln = l & 15;
  int rb = blockIdx.x * 64 + wv * 16;
  int arow = rb + ln;
  if (arow >= n) arow = n - 1;
  const s8v* A1p = (const s8v*)(A1 + (size_t)arow * D + lg * 8);
  const s8v* A2p = (const s8v*)(A2 + (size_t)arow * D + lg * 8);
  f32x4 acc[8];
#pragma unroll
  for (int f = 0; f < 8; ++f) acc[f] = (f32x4){0.f, 0.f, 0.f, 0.f};

#pragma unroll
  for (int ks = 0; ks < 4; ++ks) {
    s8v a1 = A1p[ks * 4];
    s8v a2 = A2p[ks * 4];
#pragma unroll
    for (int f = 0; f < 8; ++f) {
      const s8v* B1p = (const s8v*)(W1 + (size_t)(f * 16 + ln) * D + lg * 8);
      s8v b1 = B1p[ks * 4];
      acc[f] = __builtin_amdgcn_mfma_f32_16x16x32_bf16(a1, b1, acc[f], 0, 0, 0);
    }
#pragma unroll
    for (int f = 0; f < 8; ++f) {
      const s8v* B2p = (const s8v*)(W2 + (size_t)(f * 16 + ln) * D + lg * 8);
      s8v b2 = B2p[ks * 4];
      acc[f] = __builtin_amdgcn_mfma_f32_16x16x32_bf16(a2, b2, acc[f], 0, 0, 0);
    }
  }

#pragma unroll
  for (int r = 0; r < 4; ++r) {
    int gr = rb + 4 * lg + r;
    float v[8];
#pragma unroll
    for (int f = 0; f < 8; ++f) v[f] = acc[f][r] + bias[f * 16 + ln];
    if (MODE == 0) {
      float ss = 0.f;
#pragma unroll
      for (int f = 0; f < 8; ++f) ss += v[f] * v[f];
      ss += __shfl_xor(ss, 1);
      ss += __shfl_xor(ss, 2);
      ss += __shfl_xor(ss, 4);
      ss += __shfl_xor(ss, 8);
      float sc = 1.0f / fmaxf(sqrtf(ss), 1e-12f);
      if (gr < n) {
        unsigned short* out = (unsigned short*)outv;
#pragma unroll
        for (int f = 0; f < 8; ++f) {
          float o = fmaxf(v[f] * sc, 0.f);
          out[(size_t)gr * D + f * 16 + ln] = f2bf(o);
        }
      }
    } else {
      if (gr < n) {
        float* out = (float*)outv;
#pragma unroll
        for (int f = 0; f < 8; ++f) out[(size_t)gr * D + f * 16 + ln] = v[f];
      }
    }
  }
}

extern "C" void kernel_launch(void* const* d_in, const int* in_sizes, int n_in,
                              void* d_out, int out_size, void* d_ws, size_t ws_size,
                              hipStream_t stream) {
  const float* x   = (const float*)d_in[0];
  const int*   ei  = (const int*)d_in[1];
  const float* Wp  = (const float*)d_in[2];
  const float* bp  = (const float*)d_in[3];
  const float* Wl  = (const float*)d_in[4];
  const float* bl  = (const float*)d_in[5];
  const float* Wr  = (const float*)d_in[6];
  const float* Wlo = (const float*)d_in[7];
  const float* blo = (const float*)d_in[8];
  const float* Wro = (const float*)d_in[9];

  const int N = in_sizes[0] / D;  // 100000
  const int E = in_sizes[1] / 2;  // 1600000
  const int* srcIdx = ei;
  const int* dstIdx = ei + E;

  const size_t ND = (size_t)N * D;

  unsigned short* xb   = (unsigned short*)d_ws;   // N*D bf16
  unsigned short* h    = xb + ND;
  unsigned short* aggB = h + ND;                  // aliased: pairs (int2, E) during CSR build
  unsigned short* x2   = aggB + ND;
  unsigned short* Wb   = x2 + ND;                 // 8*16384 bf16
  int* deg       = (int*)(Wb + 8 * 16384);
  int* row_start = deg + N;
  float* inv_deg = (float*)(row_start + N);
  int* bsums     = (int*)(inv_deg + N);           // 256
  int* cursor    = bsums + 256;                   // 512
  int* csr       = cursor + 512;                  // E

  int2* pairs = (int2*)aggB;

  unsigned short* Wpb0 = Wb;
  unsigned short* Wpb1 = Wb + 16384;
  unsigned short* Wlb0 = Wb + 2 * 16384;
  unsigned short* Wlb1 = Wb + 3 * 16384;
  unsigned short* Wrb0 = Wb + 4 * 16384;
  unsigned short* Wrb1 = Wb + 5 * 16384;
  unsigned short* Wlob = Wb + 6 * 16384;
  unsigned short* Wrob = Wb + 7 * 16384;

  unsigned short* x1 = (unsigned short*)d_out;  // scratch until final GEMM

  int gE = (E + 255) / 256;
  int NB = (N + 1023) / 1024;
  int gG = (N + 63) / 64;
  int gW = (N + 3) / 4;
  int KB = (N + 255) / 256;          // buckets
  int gA = (E + 4095) / 4096;

  // ---- weights cvt + deg zero ----
  k_cvt_w<<<128, 256, 0, stream>>>(Wp, Wl, Wr, Wlo, Wro, Wb, deg, N);

  // ---- CSR build ----
  k_count_deg<<<gE, 256, 0, stream>>>(dstIdx, deg, E);
  k_scan1<<<NB, 256, 0, stream>>>(deg, row_start, bsums, N);
  k_scan2<<<1, 128, 0, stream>>>(bsums, NB);
  k_scan3<<<(N + 255) / 256, 256, 0, stream>>>(row_start, bsums, deg, inv_deg, N);
  k_cursor<<<2, 256, 0, stream>>>(row_start, cursor, N, E);
  k_partA<<<gA, 256, 0, stream>>>(srcIdx, dstIdx, cursor, pairs, E);
  k_partB<<<KB, 256, 0, stream>>>(pairs, row_start, csr, N, E);

  // ---- layer 0 ----
  k_gemm_proj<1><<<gG, 256, 0, stream>>>(x, Wpb0, bp, h, xb, N);
  k_aggregate<<<gW, 256, 0, stream>>>(h, aggB, row_start, deg, inv_deg, csr, N);
  k_gemm_dual<0><<<gG, 256, 0, stream>>>(aggB, Wlb0, bl, xb, Wrb0, (void*)x1, N);

  // ---- layer 1 ----
  k_gemm_proj<0><<<gG, 256, 0, stream>>>(x1, Wpb1, bp + D, h, nullptr, N);
  k_aggregate<<<gW, 256, 0, stream>>>(h, aggB, row_start, deg, inv_deg, csr, N);
  k_gemm_dual<0><<<gG, 256, 0, stream>>>(aggB, Wlb1, bl + D, x1, Wrb1, (void*)x2, N);

  // ---- final layer ----
  k_aggregate<<<gW, 256, 0, stream>>>(x2, aggB, row_start, deg, inv_deg, csr, N);
  k_gemm_dual<1><<<gG, 256, 0, stream>>>(aggB, Wlob, blo, x2, Wrob, d_out, N);
}

// Round 4
// 486.964 us; speedup vs baseline: 4.4865x; 1.2389x over previous
//
#include <hip/hip_runtime.h>
#include <math.h>

#define D 128

typedef short s8v __attribute__((ext_vector_type(8)));
typedef float f32x4 __attribute__((ext_vector_type(4)));
typedef unsigned short u16x8 __attribute__((ext_vector_type(8)));

__device__ __forceinline__ unsigned short f2bf(float f) {
  union { float f; unsigned u; } c; c.f = f;
  unsigned u = c.u;
  unsigned r = (u + 0x7fffu + ((u >> 16) & 1u)) >> 16;
  return (unsigned short)r;
}
__device__ __forceinline__ float bf2f(unsigned short b) {
  union { unsigned u; float f; } c; c.u = ((unsigned)b) << 16;
  return c.f;
}

// ---------------- merged weight cvt + bucketCnt zero ----------------
__global__ __launch_bounds__(256) void k_cvt_w(const float* __restrict__ Wp,
                                               const float* __restrict__ Wl,
                                               const float* __restrict__ Wr,
                                               const float* __restrict__ Wlo,
                                               const float* __restrict__ Wro,
                                               unsigned short* __restrict__ Wb,
                                               int* __restrict__ bucketCnt) {
  int i = blockIdx.x * 256 + threadIdx.x;  // float4 units, 0..32767
  const float* s;
  int off;
  if (i < 8192)       { s = Wp;  off = 0; }
  else if (i < 16384) { s = Wl;  off = 8192; }
  else if (i < 24576) { s = Wr;  off = 16384; }
  else if (i < 28672) { s = Wlo; off = 24576; }
  else                { s = Wro; off = 28672; }
  float4 a = ((const float4*)s)[i - off];
  ushort4 o;
  o.x = f2bf(a.x); o.y = f2bf(a.y); o.z = f2bf(a.z); o.w = f2bf(a.w);
  ((ushort4*)Wb)[i] = o;
  if (i < 512) bucketCnt[i] = 0;
}

// ---------------- bucket counting (bucket = 256 dst nodes) ----------------
__global__ __launch_bounds__(256) void k_bucket_count(const int* __restrict__ dst,
                                                      int* __restrict__ bucketCnt, int E_) {
  __shared__ int hist[512];
  int t = threadIdx.x;
  hist[t] = 0; hist[t + 256] = 0;
  __syncthreads();
  int base = blockIdx.x * 4096;
#pragma unroll
  for (int i = 0; i < 16; i++) {
    int e = base + i * 256 + t;
    if (e < E_) atomicAdd(&hist[dst[e] >> 8], 1);
  }
  __syncthreads();
  int c = hist[t];       if (c) atomicAdd(&bucketCnt[t], c);
  c = hist[t + 256];     if (c) atomicAdd(&bucketCnt[t + 256], c);
}

// single block: exclusive scan of 512 bucket counts
__global__ __launch_bounds__(512) void k_bucket_scan(const int* __restrict__ cnt,
                                                     int* __restrict__ base,
                                                     int* __restrict__ cursor,
                                                     int* __restrict__ row_start,
                                                     int n, int E_) {
  __shared__ int bs[512];
  int t = threadIdx.x;
  int orig = cnt[t];
  bs[t] = orig;
  __syncthreads();
  for (int off = 1; off < 512; off <<= 1) {
    int x = (t >= off) ? bs[t - off] : 0;
    __syncthreads();
    bs[t] += x;
    __syncthreads();
  }
  int ex = bs[t] - orig;
  base[t] = ex;
  cursor[t] = ex;
  if (t == 511) base[512] = bs[511];
  if (t == 0) row_start[n] = E_;   // sentinel
}

// Pass A: bin (src,dst) pairs into bucket regions. 16384 edges / block.
__global__ __launch_bounds__(1024) void k_partA(const int* __restrict__ src,
                                                const int* __restrict__ dst,
                                                int* __restrict__ cursor,
                                                int2* __restrict__ pairs, int E_) {
  __shared__ int hist[512];
  __shared__ int gbase[512];
  int t = threadIdx.x;
  int base = blockIdx.x * 16384;
  if (t < 512) hist[t] = 0;
  __syncthreads();
  int s_[16], d_[16];
#pragma unroll
  for (int i = 0; i < 16; i++) {
    int e = base + i * 1024 + t;
    if (e < E_) {
      s_[i] = src[e];
      d_[i] = dst[e];
      atomicAdd(&hist[d_[i] >> 8], 1);
    } else {
      d_[i] = -1;
    }
  }
  __syncthreads();
  if (t < 512) {
    int c = hist[t];
    gbase[t] = c ? atomicAdd(&cursor[t], c) : 0;
    hist[t] = 0;
  }
  __syncthreads();
#pragma unroll
  for (int i = 0; i < 16; i++) {
    if (d_[i] >= 0) {
      int k = d_[i] >> 8;
      int r = atomicAdd(&hist[k], 1);
      pairs[gbase[k] + r] = make_int2(s_[i], d_[i]);
    }
  }
}

// Pass B: one block per bucket; LDS hist -> scan -> row_start + csr fill.
__global__ __launch_bounds__(256) void k_partB(const int2* __restrict__ pairs,
                                               const int* __restrict__ bucketBase,
                                               int* __restrict__ row_start,
                                               int* __restrict__ csr, int n) {
  __shared__ int cnt[256];
  __shared__ int scn[256];
  int k = blockIdx.x, t = threadIdx.x;
  int node0 = k << 8;
  int pbeg = bucketBase[k], pend = bucketBase[k + 1];
  cnt[t] = 0;
  __syncthreads();
  for (int p = pbeg + t; p < pend; p += 256) atomicAdd(&cnt[pairs[p].y & 255], 1);
  __syncthreads();
  int c = cnt[t];
  scn[t] = c;
  __syncthreads();
  for (int off = 1; off < 256; off <<= 1) {
    int x = (t >= off) ? scn[t - off] : 0;
    __syncthreads();
    scn[t] += x;
    __syncthreads();
  }
  int ex = scn[t] - c;
  int node = node0 + t;
  if (node < n) row_start[node] = pbeg + ex;
  __syncthreads();
  cnt[t] = pbeg + ex;   // running cursor per node
  __syncthreads();
  for (int p = pbeg + t; p < pend; p += 256) {
    int2 pr = pairs[p];
    int slot = atomicAdd(&cnt[pr.y & 255], 1);
    csr[slot] = pr.x;
  }
}

// ---------------- mean aggregation: wave/node, 4 rows per load ----------------
__global__ __launch_bounds__(256) void k_aggregate(const unsigned short* __restrict__ h,
                                                   unsigned short* __restrict__ agg,
                                                   const int* __restrict__ row_start,
                                                   const int* __restrict__ csr, int n) {
  int w = (blockIdx.x * 256 + threadIdx.x) >> 6;
  int lane = threadIdx.x & 63;
  if (w >= n) return;
  int rs0 = row_start[w];
  int rs1 = row_start[w + 1];
  int dc = rs1 - rs0;
  int grp = lane >> 4, li = lane & 15;
  const unsigned short* hB = h + li * 8;
  float acc[8];
#pragma unroll
  for (int q = 0; q < 8; q++) acc[q] = 0.f;

  for (int base = 0; base < dc; base += 64) {
    int m = min(64, dc - base);
    int idx = 0;
    if (lane < m) idx = csr[rs0 + base + lane];
    int nIter = (m + 3) >> 2;
    int j = 0;
    for (; j + 1 < nIter; j += 2) {
      int p0 = 4 * j + grp, p1 = p0 + 4;
      int sA = __shfl(idx, p0 < m ? p0 : m - 1);
      int sB = __shfl(idx, p1 < m ? p1 : m - 1);
      u16x8 vA = *(const u16x8*)(hB + (size_t)sA * D);
      u16x8 vB = *(const u16x8*)(hB + (size_t)sB * D);
      if (p0 < m) {
#pragma unroll
        for (int q = 0; q < 8; q++) acc[q] += bf2f((unsigned short)vA[q]);
      }
      if (p1 < m) {
#pragma unroll
        for (int q = 0; q < 8; q++) acc[q] += bf2f((unsigned short)vB[q]);
      }
    }
    if (j < nIter) {
      int p0 = 4 * j + grp;
      int sA = __shfl(idx, p0 < m ? p0 : m - 1);
      u16x8 vA = *(const u16x8*)(hB + (size_t)sA * D);
      if (p0 < m) {
#pragma unroll
        for (int q = 0; q < 8; q++) acc[q] += bf2f((unsigned short)vA[q]);
      }
    }
  }

#pragma unroll
  for (int q = 0; q < 8; q++) {
    acc[q] += __shfl_xor(acc[q], 16);
    acc[q] += __shfl_xor(acc[q], 32);
  }
  if (grp == 0) {
    float iv = 1.0f / (float)(dc > 0 ? dc : 1);
    u16x8 o;
#pragma unroll
    for (int q = 0; q < 8; q++) o[q] = f2bf(acc[q] * iv);
    *(u16x8*)(agg + (size_t)w * D + li * 8) = o;
  }
}

// ---------------- projection GEMM: out = relu(A @ W^T + b) -> bf16 ----------------
template <int CVT>
__global__ __launch_bounds__(256) void k_gemm_proj(const void* __restrict__ Av,
                                                   const unsigned short* __restrict__ W,
                                                   const float* __restrict__ bias,
                                                   unsigned short* __restrict__ out,
                                                   unsigned short* __restrict__ xb_out,
                                                   int n) {
  int t = threadIdx.x;
  int wv = t >> 6, l = t & 63, lg = l >> 4, ln = l & 15;
  int rb = blockIdx.x * 64 + wv * 16;
  int arow = rb + ln;
  if (arow >= n) arow = n - 1;

  s8v a[4];
  if (CVT) {
    const float* Af = (const float*)Av + (size_t)arow * D + lg * 8;
#pragma unroll
    for (int ks = 0; ks < 4; ++ks) {
      float4 f0 = *(const float4*)(Af + ks * 32);
      float4 f1 = *(const float4*)(Af + ks * 32 + 4);
      s8v av;
      av[0] = (short)f2bf(f0.x); av[1] = (short)f2bf(f0.y);
      av[2] = (short)f2bf(f0.z); av[3] = (short)f2bf(f0.w);
      av[4] = (short)f2bf(f1.x); av[5] = (short)f2bf(f1.y);
      av[6] = (short)f2bf(f1.z); av[7] = (short)f2bf(f1.w);
      a[ks] = av;
      if (xb_out) *(s8v*)(xb_out + (size_t)arow * D + lg * 8 + ks * 32) = av;
    }
  } else {
    const s8v* Ap = (const s8v*)((const unsigned short*)Av + (size_t)arow * D + lg * 8);
#pragma unroll
    for (int ks = 0; ks < 4; ++ks) a[ks] = Ap[ks * 4];
  }

  f32x4 acc[8];
#pragma unroll
  for (int f = 0; f < 8; ++f) acc[f] = (f32x4){0.f, 0.f, 0.f, 0.f};
#pragma unroll
  for (int ks = 0; ks < 4; ++ks) {
#pragma unroll
    for (int f = 0; f < 8; ++f) {
      const s8v* Bp = (const s8v*)(W + (size_t)(f * 16 + ln) * D + lg * 8);
      s8v b = Bp[ks * 4];
      acc[f] = __builtin_amdgcn_mfma_f32_16x16x32_bf16(a[ks], b, acc[f], 0, 0, 0);
    }
  }

#pragma unroll
  for (int r = 0; r < 4; ++r) {
    int gr = rb + 4 * lg + r;
    if (gr < n) {
#pragma unroll
      for (int f = 0; f < 8; ++f) {
        int c = f * 16 + ln;
        float v = acc[f][r] + bias[c];
        v = fmaxf(v, 0.f);
        out[(size_t)gr * D + c] = f2bf(v);
      }
    }
  }
}

// ---------------- dual GEMM: A1@W1^T + b + A2@W2^T ----------------
// MODE 0: L2-normalize rows then relu, store bf16. MODE 1: store fp32.
template <int MODE>
__global__ __launch_bounds__(256) void k_gemm_dual(const unsigned short* __restrict__ A1,
                                                   const unsigned short* __restrict__ W1,
                                                   const float* __restrict__ bias,
                                                   const unsigned short* __restrict__ A2,
                                                   const unsigned short* __restrict__ W2,
                                                   void* __restrict__ outv, int n) {
  int t = threadIdx.x;
  int wv = t >> 6, l = t & 63, lg = l >> 4, ln = l & 15;
  int rb = blockIdx.x * 64 + wv * 16;
  int arow = rb + ln;
  if (arow >= n) arow = n - 1;
  const s8v* A1p = (const s8v*)(A1 + (size_t)arow * D + lg * 8);
  const s8v* A2p = (const s8v*)(A2 + (size_t)arow * D + lg * 8);
  f32x4 acc[8];
#pragma unroll
  for (int f = 0; f < 8; ++f) acc[f] = (f32x4){0.f, 0.f, 0.f, 0.f};

#pragma unroll
  for (int ks = 0; ks < 4; ++ks) {
    s8v a1 = A1p[ks * 4];
    s8v a2 = A2p[ks * 4];
#pragma unroll
    for (int f = 0; f < 8; ++f) {
      const s8v* B1p = (const s8v*)(W1 + (size_t)(f * 16 + ln) * D + lg * 8);
      s8v b1 = B1p[ks * 4];
      acc[f] = __builtin_amdgcn_mfma_f32_16x16x32_bf16(a1, b1, acc[f], 0, 0, 0);
    }
#pragma unroll
    for (int f = 0; f < 8; ++f) {
      const s8v* B2p = (const s8v*)(W2 + (size_t)(f * 16 + ln) * D + lg * 8);
      s8v b2 = B2p[ks * 4];
      acc[f] = __builtin_amdgcn_mfma_f32_16x16x32_bf16(a2, b2, acc[f], 0, 0, 0);
    }
  }

#pragma unroll
  for (int r = 0; r < 4; ++r) {
    int gr = rb + 4 * lg + r;
    float v[8];
#pragma unroll
    for (int f = 0; f < 8; ++f) v[f] = acc[f][r] + bias[f * 16 + ln];
    if (MODE == 0) {
      float ss = 0.f;
#pragma unroll
      for (int f = 0; f < 8; ++f) ss += v[f] * v[f];
      ss += __shfl_xor(ss, 1);
      ss += __shfl_xor(ss, 2);
      ss += __shfl_xor(ss, 4);
      ss += __shfl_xor(ss, 8);
      float sc = 1.0f / fmaxf(sqrtf(ss), 1e-12f);
      if (gr < n) {
        unsigned short* out = (unsigned short*)outv;
#pragma unroll
        for (int f = 0; f < 8; ++f) {
          float o = fmaxf(v[f] * sc, 0.f);
          out[(size_t)gr * D + f * 16 + ln] = f2bf(o);
        }
      }
    } else {
      if (gr < n) {
        float* out = (float*)outv;
#pragma unroll
        for (int f = 0; f < 8; ++f) out[(size_t)gr * D + f * 16 + ln] = v[f];
      }
    }
  }
}

extern "C" void kernel_launch(void* const* d_in, const int* in_sizes, int n_in,
                              void* d_out, int out_size, void* d_ws, size_t ws_size,
                              hipStream_t stream) {
  const float* x   = (const float*)d_in[0];
  const int*   ei  = (const int*)d_in[1];
  const float* Wp  = (const float*)d_in[2];
  const float* bp  = (const float*)d_in[3];
  const float* Wl  = (const float*)d_in[4];
  const float* bl  = (const float*)d_in[5];
  const float* Wr  = (const float*)d_in[6];
  const float* Wlo = (const float*)d_in[7];
  const float* blo = (const float*)d_in[8];
  const float* Wro = (const float*)d_in[9];

  const int N = in_sizes[0] / D;  // 100000
  const int E = in_sizes[1] / 2;  // 1600000
  const int* srcIdx = ei;
  const int* dstIdx = ei + E;

  const size_t ND = (size_t)N * D;

  unsigned short* xb   = (unsigned short*)d_ws;   // N*D bf16
  unsigned short* h    = xb + ND;
  unsigned short* aggB = h + ND;                  // aliased: pairs (int2, E) during CSR build
  unsigned short* x2   = aggB + ND;
  unsigned short* Wb   = x2 + ND;                 // 8*16384 bf16
  int* row_start  = (int*)(Wb + 8 * 16384);       // N+1
  int* bucketCnt  = row_start + N + 1;            // 512
  int* bucketBase = bucketCnt + 512;              // 513
  int* cursor     = bucketBase + 513;             // 512
  int* csr        = cursor + 512;                 // E

  int2* pairs = (int2*)aggB;

  unsigned short* Wpb0 = Wb;
  unsigned short* Wpb1 = Wb + 16384;
  unsigned short* Wlb0 = Wb + 2 * 16384;
  unsigned short* Wlb1 = Wb + 3 * 16384;
  unsigned short* Wrb0 = Wb + 4 * 16384;
  unsigned short* Wrb1 = Wb + 5 * 16384;
  unsigned short* Wlob = Wb + 6 * 16384;
  unsigned short* Wrob = Wb + 7 * 16384;

  unsigned short* x1 = (unsigned short*)d_out;  // scratch until final GEMM

  int gG = (N + 63) / 64;
  int gW = (N + 3) / 4;
  int KB = (N + 255) / 256;            // buckets
  int gBC = (E + 4095) / 4096;
  int gA  = (E + 16383) / 16384;

  // ---- weights cvt + bucketCnt zero ----
  k_cvt_w<<<128, 256, 0, stream>>>(Wp, Wl, Wr, Wlo, Wro, Wb, bucketCnt);

  // ---- CSR build (bucketized, no global scans) ----
  k_bucket_count<<<gBC, 256, 0, stream>>>(dstIdx, bucketCnt, E);
  k_bucket_scan<<<1, 512, 0, stream>>>(bucketCnt, bucketBase, cursor, row_start, N, E);
  k_partA<<<gA, 1024, 0, stream>>>(srcIdx, dstIdx, cursor, pairs, E);
  k_partB<<<KB, 256, 0, stream>>>(pairs, bucketBase, row_start, csr, N);

  // ---- layer 0 ----
  k_gemm_proj<1><<<gG, 256, 0, stream>>>(x, Wpb0, bp, h, xb, N);
  k_aggregate<<<gW, 256, 0, stream>>>(h, aggB, row_start, csr, N);
  k_gemm_dual<0><<<gG, 256, 0, stream>>>(aggB, Wlb0, bl, xb, Wrb0, (void*)x1, N);

  // ---- layer 1 ----
  k_gemm_proj<0><<<gG, 256, 0, stream>>>(x1, Wpb1, bp + D, h, nullptr, N);
  k_aggregate<<<gW, 256, 0, stream>>>(h, aggB, row_start, csr, N);
  k_gemm_dual<0><<<gG, 256, 0, stream>>>(aggB, Wlb1, bl + D, x1, Wrb1, (void*)x2, N);

  // ---- final layer ----
  k_aggregate<<<gW, 256, 0, stream>>>(x2, aggB, row_start, csr, N);
  k_gemm_dual<1><<<gG, 256, 0, stream>>>(aggB, Wlob, blo, x2, Wrob, d_out, N);
}

// Round 5
// 329.278 us; speedup vs baseline: 6.6350x; 1.4789x over previous
//
#include <hip/hip_runtime.h>
#include <math.h>

#define D 128

typedef short s8v __attribute__((ext_vector_type(8)));
typedef float f32x4 __attribute__((ext_vector_type(4)));
typedef unsigned short u16x8 __attribute__((ext_vector_type(8)));

__device__ __forceinline__ unsigned short f2bf(float f) {
  union { float f; unsigned u; } c; c.f = f;
  unsigned u = c.u;
  unsigned r = (u + 0x7fffu + ((u >> 16) & 1u)) >> 16;
  return (unsigned short)r;
}
__device__ __forceinline__ float bf2f(unsigned short b) {
  union { unsigned u; float f; } c; c.u = ((unsigned)b) << 16;
  return c.f;
}

// ---------------- merged weight cvt + bucketCnt zero ----------------
__global__ __launch_bounds__(256) void k_cvt_w(const float* __restrict__ Wp,
                                               const float* __restrict__ Wl,
                                               const float* __restrict__ Wr,
                                               const float* __restrict__ Wlo,
                                               const float* __restrict__ Wro,
                                               unsigned short* __restrict__ Wb,
                                               int* __restrict__ bucketCnt) {
  int i = blockIdx.x * 256 + threadIdx.x;  // float4 units, 0..32767
  const float* s;
  int off;
  if (i < 8192)       { s = Wp;  off = 0; }
  else if (i < 16384) { s = Wl;  off = 8192; }
  else if (i < 24576) { s = Wr;  off = 16384; }
  else if (i < 28672) { s = Wlo; off = 24576; }
  else                { s = Wro; off = 28672; }
  float4 a = ((const float4*)s)[i - off];
  ushort4 o;
  o.x = f2bf(a.x); o.y = f2bf(a.y); o.z = f2bf(a.z); o.w = f2bf(a.w);
  ((ushort4*)Wb)[i] = o;
  if (i < 512) bucketCnt[i] = 0;
}

// ---------------- bucket counting (bucket = 256 dst nodes) ----------------
__global__ __launch_bounds__(256) void k_bucket_count(const int* __restrict__ dst,
                                                      int* __restrict__ bucketCnt, int E_) {
  __shared__ int hist[512];
  int t = threadIdx.x;
  hist[t] = 0; hist[t + 256] = 0;
  __syncthreads();
  int base = blockIdx.x * 4096;
#pragma unroll
  for (int i = 0; i < 16; i++) {
    int e = base + i * 256 + t;
    if (e < E_) atomicAdd(&hist[dst[e] >> 8], 1);
  }
  __syncthreads();
  int c = hist[t];       if (c) atomicAdd(&bucketCnt[t], c);
  c = hist[t + 256];     if (c) atomicAdd(&bucketCnt[t + 256], c);
}

// single block: exclusive scan of 512 bucket counts
__global__ __launch_bounds__(512) void k_bucket_scan(const int* __restrict__ cnt,
                                                     int* __restrict__ base,
                                                     int* __restrict__ cursor,
                                                     int* __restrict__ row_start,
                                                     int n, int E_) {
  __shared__ int bs[512];
  int t = threadIdx.x;
  int orig = cnt[t];
  bs[t] = orig;
  __syncthreads();
  for (int off = 1; off < 512; off <<= 1) {
    int x = (t >= off) ? bs[t - off] : 0;
    __syncthreads();
    bs[t] += x;
    __syncthreads();
  }
  int ex = bs[t] - orig;
  base[t] = ex;
  cursor[t] = ex;
  if (t == 511) base[512] = bs[511];
  if (t == 0) row_start[n] = E_;   // sentinel
}

// Pass A: bin (src,dst) pairs into bucket regions. 16384 edges / block.
__global__ __launch_bounds__(1024) void k_partA(const int* __restrict__ src,
                                                const int* __restrict__ dst,
                                                int* __restrict__ cursor,
                                                int2* __restrict__ pairs, int E_) {
  __shared__ int hist[512];
  __shared__ int gbase[512];
  int t = threadIdx.x;
  int base = blockIdx.x * 16384;
  if (t < 512) hist[t] = 0;
  __syncthreads();
  int s_[16], d_[16];
#pragma unroll
  for (int i = 0; i < 16; i++) {
    int e = base + i * 1024 + t;
    if (e < E_) {
      s_[i] = src[e];
      d_[i] = dst[e];
      atomicAdd(&hist[d_[i] >> 8], 1);
    } else {
      d_[i] = -1;
    }
  }
  __syncthreads();
  if (t < 512) {
    int c = hist[t];
    gbase[t] = c ? atomicAdd(&cursor[t], c) : 0;
    hist[t] = 0;
  }
  __syncthreads();
#pragma unroll
  for (int i = 0; i < 16; i++) {
    if (d_[i] >= 0) {
      int k = d_[i] >> 8;
      int r = atomicAdd(&hist[k], 1);
      pairs[gbase[k] + r] = make_int2(s_[i], d_[i]);
    }
  }
}

// Pass B: one block per bucket; LDS hist -> scan -> row_start + csr fill.
__global__ __launch_bounds__(256) void k_partB(const int2* __restrict__ pairs,
                                               const int* __restrict__ bucketBase,
                                               int* __restrict__ row_start,
                                               int* __restrict__ csr, int n) {
  __shared__ int cnt[256];
  __shared__ int scn[256];
  int k = blockIdx.x, t = threadIdx.x;
  int node0 = k << 8;
  int pbeg = bucketBase[k], pend = bucketBase[k + 1];
  cnt[t] = 0;
  __syncthreads();
  for (int p = pbeg + t; p < pend; p += 256) atomicAdd(&cnt[pairs[p].y & 255], 1);
  __syncthreads();
  int c = cnt[t];
  scn[t] = c;
  __syncthreads();
  for (int off = 1; off < 256; off <<= 1) {
    int x = (t >= off) ? scn[t - off] : 0;
    __syncthreads();
    scn[t] += x;
    __syncthreads();
  }
  int ex = scn[t] - c;
  int node = node0 + t;
  if (node < n) row_start[node] = pbeg + ex;
  __syncthreads();
  cnt[t] = pbeg + ex;   // running cursor per node
  __syncthreads();
  for (int p = pbeg + t; p < pend; p += 256) {
    int2 pr = pairs[p];
    int slot = atomicAdd(&cnt[pr.y & 255], 1);
    csr[slot] = pr.x;
  }
}

// ---------------- mean aggregation: wave/node, 4 rows per load ----------------
__global__ __launch_bounds__(256) void k_aggregate(const unsigned short* __restrict__ h,
                                                   unsigned short* __restrict__ agg,
                                                   const int* __restrict__ row_start,
                                                   const int* __restrict__ csr, int n) {
  int w = (blockIdx.x * 256 + threadIdx.x) >> 6;
  int lane = threadIdx.x & 63;
  if (w >= n) return;
  int rs0 = row_start[w];
  int rs1 = row_start[w + 1];
  int dc = rs1 - rs0;
  int grp = lane >> 4, li = lane & 15;
  const unsigned short* hB = h + li * 8;
  float acc[8];
#pragma unroll
  for (int q = 0; q < 8; q++) acc[q] = 0.f;

  for (int base = 0; base < dc; base += 64) {
    int m = min(64, dc - base);
    int idx = 0;
    if (lane < m) idx = csr[rs0 + base + lane];
    int nIter = (m + 3) >> 2;
    int j = 0;
    for (; j + 1 < nIter; j += 2) {
      int p0 = 4 * j + grp, p1 = p0 + 4;
      int sA = __shfl(idx, p0 < m ? p0 : m - 1);
      int sB = __shfl(idx, p1 < m ? p1 : m - 1);
      u16x8 vA = *(const u16x8*)(hB + (size_t)sA * D);
      u16x8 vB = *(const u16x8*)(hB + (size_t)sB * D);
      if (p0 < m) {
#pragma unroll
        for (int q = 0; q < 8; q++) acc[q] += bf2f((unsigned short)vA[q]);
      }
      if (p1 < m) {
#pragma unroll
        for (int q = 0; q < 8; q++) acc[q] += bf2f((unsigned short)vB[q]);
      }
    }
    if (j < nIter) {
      int p0 = 4 * j + grp;
      int sA = __shfl(idx, p0 < m ? p0 : m - 1);
      u16x8 vA = *(const u16x8*)(hB + (size_t)sA * D);
      if (p0 < m) {
#pragma unroll
        for (int q = 0; q < 8; q++) acc[q] += bf2f((unsigned short)vA[q]);
      }
    }
  }

#pragma unroll
  for (int q = 0; q < 8; q++) {
    acc[q] += __shfl_xor(acc[q], 16);
    acc[q] += __shfl_xor(acc[q], 32);
  }
  if (grp == 0) {
    float iv = 1.0f / (float)(dc > 0 ? dc : 1);
    u16x8 o;
#pragma unroll
    for (int q = 0; q < 8; q++) o[q] = f2bf(acc[q] * iv);
    *(u16x8*)(agg + (size_t)w * D + li * 8) = o;
  }
}

// LDS fragment address: logical (row r, chunk c) stored at chunk (r*16 + (c ^ (r&7)))
__device__ __forceinline__ int swz_chunk(int r, int c) { return (r << 4) + (c ^ (r & 7)); }

// ---------------- projection GEMM (LDS-staged W): out = relu(A @ W^T + b) -> bf16 ----
// 512 thr = 8 waves, 128 rows/block. CVT=1: A fp32, also writes bf16 A to xb_out.
template <int CVT>
__global__ __launch_bounds__(512, 4) void k_gemm_proj(const void* __restrict__ Av,
                                                      const unsigned short* __restrict__ W,
                                                      const float* __restrict__ bias,
                                                      unsigned short* __restrict__ out,
                                                      unsigned short* __restrict__ xb_out,
                                                      int n) {
  __shared__ __align__(16) unsigned short Wlds[128 * 128];
  int t = threadIdx.x;
#pragma unroll
  for (int i = 0; i < 4; ++i) {
    int idx = t + i * 512;          // chunk 0..2047
    int r = idx >> 4, k = idx & 15;
    int c = k ^ (r & 7);
    *(u16x8*)&Wlds[idx * 8] = *(const u16x8*)(W + r * 128 + c * 8);
  }
  __syncthreads();

  int wv = t >> 6, l = t & 63, lg = l >> 4, ln = l & 15;
  int rb = blockIdx.x * 128 + wv * 16;
  int arow = rb + ln;
  if (arow >= n) arow = n - 1;

  s8v a[4];
  if (CVT) {
    const float* Af = (const float*)Av + (size_t)arow * D + lg * 8;
#pragma unroll
    for (int ks = 0; ks < 4; ++ks) {
      float4 f0 = *(const float4*)(Af + ks * 32);
      float4 f1 = *(const float4*)(Af + ks * 32 + 4);
      s8v av;
      av[0] = (short)f2bf(f0.x); av[1] = (short)f2bf(f0.y);
      av[2] = (short)f2bf(f0.z); av[3] = (short)f2bf(f0.w);
      av[4] = (short)f2bf(f1.x); av[5] = (short)f2bf(f1.y);
      av[6] = (short)f2bf(f1.z); av[7] = (short)f2bf(f1.w);
      a[ks] = av;
      if (xb_out) *(s8v*)(xb_out + (size_t)arow * D + lg * 8 + ks * 32) = av;
    }
  } else {
    const s8v* Ap = (const s8v*)((const unsigned short*)Av + (size_t)arow * D + lg * 8);
#pragma unroll
    for (int ks = 0; ks < 4; ++ks) a[ks] = Ap[ks * 4];
  }

  f32x4 acc[8];
#pragma unroll
  for (int f = 0; f < 8; ++f) acc[f] = (f32x4){0.f, 0.f, 0.f, 0.f};
#pragma unroll
  for (int ks = 0; ks < 4; ++ks) {
#pragma unroll
    for (int f = 0; f < 8; ++f) {
      s8v b = *(const s8v*)&Wlds[swz_chunk(f * 16 + ln, ks * 4 + lg) * 8];
      acc[f] = __builtin_amdgcn_mfma_f32_16x16x32_bf16(a[ks], b, acc[f], 0, 0, 0);
    }
  }

#pragma unroll
  for (int r = 0; r < 4; ++r) {
    int gr = rb + 4 * lg + r;
    if (gr < n) {
#pragma unroll
      for (int f = 0; f < 8; ++f) {
        int c = f * 16 + ln;
        float v = acc[f][r] + bias[c];
        v = fmaxf(v, 0.f);
        out[(size_t)gr * D + c] = f2bf(v);
      }
    }
  }
}

// ---------------- dual GEMM (LDS-staged W1+W2): A1@W1^T + b + A2@W2^T ----------------
// MODE 0: L2-normalize rows then relu, store bf16. MODE 1: store fp32.
template <int MODE>
__global__ __launch_bounds__(512, 4) void k_gemm_dual(const unsigned short* __restrict__ A1,
                                                      const unsigned short* __restrict__ W1,
                                                      const float* __restrict__ bias,
                                                      const unsigned short* __restrict__ A2,
                                                      const unsigned short* __restrict__ W2,
                                                      void* __restrict__ outv, int n) {
  __shared__ __align__(16) unsigned short Wlds[2 * 128 * 128];
  int t = threadIdx.x;
#pragma unroll
  for (int i = 0; i < 8; ++i) {
    int idx = t + i * 512;          // chunk 0..4095
    int mat = idx >> 11;
    int rem = idx & 2047;
    int r = rem >> 4, k = rem & 15;
    int c = k ^ (r & 7);
    const unsigned short* src = (mat ? W2 : W1) + r * 128 + c * 8;
    *(u16x8*)&Wlds[idx * 8] = *(const u16x8*)src;
  }
  __syncthreads();

  int wv = t >> 6, l = t & 63, lg = l >> 4, ln = l & 15;
  int rb = blockIdx.x * 128 + wv * 16;
  int arow = rb + ln;
  if (arow >= n) arow = n - 1;
  const s8v* A1p = (const s8v*)(A1 + (size_t)arow * D + lg * 8);
  const s8v* A2p = (const s8v*)(A2 + (size_t)arow * D + lg * 8);
  s8v a1[4], a2[4];
#pragma unroll
  for (int ks = 0; ks < 4; ++ks) { a1[ks] = A1p[ks * 4]; a2[ks] = A2p[ks * 4]; }

  f32x4 acc[8];
#pragma unroll
  for (int f = 0; f < 8; ++f) acc[f] = (f32x4){0.f, 0.f, 0.f, 0.f};

#pragma unroll
  for (int ks = 0; ks < 4; ++ks) {
#pragma unroll
    for (int f = 0; f < 8; ++f) {
      int ch = swz_chunk(f * 16 + ln, ks * 4 + lg) * 8;
      s8v b1 = *(const s8v*)&Wlds[ch];
      s8v b2 = *(const s8v*)&Wlds[16384 + ch];
      acc[f] = __builtin_amdgcn_mfma_f32_16x16x32_bf16(a1[ks], b1, acc[f], 0, 0, 0);
      acc[f] = __builtin_amdgcn_mfma_f32_16x16x32_bf16(a2[ks], b2, acc[f], 0, 0, 0);
    }
  }

#pragma unroll
  for (int r = 0; r < 4; ++r) {
    int gr = rb + 4 * lg + r;
    float v[8];
#pragma unroll
    for (int f = 0; f < 8; ++f) v[f] = acc[f][r] + bias[f * 16 + ln];
    if (MODE == 0) {
      float ss = 0.f;
#pragma unroll
      for (int f = 0; f < 8; ++f) ss += v[f] * v[f];
      ss += __shfl_xor(ss, 1);
      ss += __shfl_xor(ss, 2);
      ss += __shfl_xor(ss, 4);
      ss += __shfl_xor(ss, 8);
      float sc = 1.0f / fmaxf(sqrtf(ss), 1e-12f);
      if (gr < n) {
        unsigned short* out = (unsigned short*)outv;
#pragma unroll
        for (int f = 0; f < 8; ++f) {
          float o = fmaxf(v[f] * sc, 0.f);
          out[(size_t)gr * D + f * 16 + ln] = f2bf(o);
        }
      }
    } else {
      if (gr < n) {
        float* out = (float*)outv;
#pragma unroll
        for (int f = 0; f < 8; ++f) out[(size_t)gr * D + f * 16 + ln] = v[f];
      }
    }
  }
}

extern "C" void kernel_launch(void* const* d_in, const int* in_sizes, int n_in,
                              void* d_out, int out_size, void* d_ws, size_t ws_size,
                              hipStream_t stream) {
  const float* x   = (const float*)d_in[0];
  const int*   ei  = (const int*)d_in[1];
  const float* Wp  = (const float*)d_in[2];
  const float* bp  = (const float*)d_in[3];
  const float* Wl  = (const float*)d_in[4];
  const float* bl  = (const float*)d_in[5];
  const float* Wr  = (const float*)d_in[6];
  const float* Wlo = (const float*)d_in[7];
  const float* blo = (const float*)d_in[8];
  const float* Wro = (const float*)d_in[9];

  const int N = in_sizes[0] / D;  // 100000
  const int E = in_sizes[1] / 2;  // 1600000
  const int* srcIdx = ei;
  const int* dstIdx = ei + E;

  const size_t ND = (size_t)N * D;

  unsigned short* xb   = (unsigned short*)d_ws;   // N*D bf16
  unsigned short* h    = xb + ND;
  unsigned short* aggB = h + ND;                  // aliased: pairs (int2, E) during CSR build
  unsigned short* x2   = aggB + ND;
  unsigned short* Wb   = x2 + ND;                 // 8*16384 bf16
  int* row_start  = (int*)(Wb + 8 * 16384);       // N+1
  int* bucketCnt  = row_start + N + 1;            // 512
  int* bucketBase = bucketCnt + 512;              // 513
  int* cursor     = bucketBase + 513;             // 512
  int* csr        = cursor + 512;                 // E

  int2* pairs = (int2*)aggB;

  unsigned short* Wpb0 = Wb;
  unsigned short* Wpb1 = Wb + 16384;
  unsigned short* Wlb0 = Wb + 2 * 16384;
  unsigned short* Wlb1 = Wb + 3 * 16384;
  unsigned short* Wrb0 = Wb + 4 * 16384;
  unsigned short* Wrb1 = Wb + 5 * 16384;
  unsigned short* Wlob = Wb + 6 * 16384;
  unsigned short* Wrob = Wb + 7 * 16384;

  unsigned short* x1 = (unsigned short*)d_out;  // scratch until final GEMM

  int gG = (N + 127) / 128;            // 512-thr GEMM blocks (128 rows each)
  int gW = (N + 3) / 4;
  int KB = (N + 255) / 256;            // buckets
  int gBC = (E + 4095) / 4096;
  int gA  = (E + 16383) / 16384;

  // ---- weights cvt + bucketCnt zero ----
  k_cvt_w<<<128, 256, 0, stream>>>(Wp, Wl, Wr, Wlo, Wro, Wb, bucketCnt);

  // ---- CSR build (bucketized, no global scans) ----
  k_bucket_count<<<gBC, 256, 0, stream>>>(dstIdx, bucketCnt, E);
  k_bucket_scan<<<1, 512, 0, stream>>>(bucketCnt, bucketBase, cursor, row_start, N, E);
  k_partA<<<gA, 1024, 0, stream>>>(srcIdx, dstIdx, cursor, pairs, E);
  k_partB<<<KB, 256, 0, stream>>>(pairs, bucketBase, row_start, csr, N);

  // ---- layer 0 ----
  k_gemm_proj<1><<<gG, 512, 0, stream>>>(x, Wpb0, bp, h, xb, N);
  k_aggregate<<<gW, 256, 0, stream>>>(h, aggB, row_start, csr, N);
  k_gemm_dual<0><<<gG, 512, 0, stream>>>(aggB, Wlb0, bl, xb, Wrb0, (void*)x1, N);

  // ---- layer 1 ----
  k_gemm_proj<0><<<gG, 512, 0, stream>>>(x1, Wpb1, bp + D, h, nullptr, N);
  k_aggregate<<<gW, 256, 0, stream>>>(h, aggB, row_start, csr, N);
  k_gemm_dual<0><<<gG, 512, 0, stream>>>(aggB, Wlb1, bl + D, x1, Wrb1, (void*)x2, N);

  // ---- final layer ----
  k_aggregate<<<gW, 256, 0, stream>>>(x2, aggB, row_start, csr, N);
  k_gemm_dual<1><<<gG, 512, 0, stream>>>(aggB, Wlob, blo, x2, Wrob, d_out, N);
}